// Round 1
// baseline (3522.272 us; speedup 1.0000x reference)
//
#include <hip/hip_runtime.h>
#include <math.h>

// Problem constants
#define BB   2
#define LL   1024
#define HH   768
#define NHH  12
#define NEE  24
#define MMM  3
#define NCC  2
#define CWW  8
#define BLK  64
#define NCLS 97
#define KB   12          // HH/BLK
#define HB   49152       // HH*BLK
#define NCP  128         // padded class dim for Wf
#define NEF  1152        // BB*NEE*NEE

// ---------------------------------------------------------------------------
// K1: e_att[b,e,h,l] = mean_m attention[b,h,ms[b,e,m]+1,l]
__global__ void k_eatt(const float* __restrict__ att_in, const int* __restrict__ ms,
                       float* __restrict__ e_att) {
    int blk = blockIdx.x;               // (b*NEE+e)*NHH + h
    int h = blk % NHH;
    int e = (blk / NHH) % NEE;
    int b = blk / (NHH * NEE);
    int base = (b * NEE + e) * MMM;
    int p0 = ms[base + 0] + 1;
    int p1 = ms[base + 1] + 1;
    int p2 = ms[base + 2] + 1;
    const float* r0 = att_in + ((size_t)(b * NHH + h) * LL + p0) * LL;
    const float* r1 = att_in + ((size_t)(b * NHH + h) * LL + p1) * LL;
    const float* r2 = att_in + ((size_t)(b * NHH + h) * LL + p2) * LL;
    float* o = e_att + ((size_t)(b * NEE + e) * NHH + h) * LL;
    for (int l = threadIdx.x; l < LL; l += blockDim.x)
        o[l] = (r0[l] + r1[l] + r2[l]) * (1.f / 3.f);
}

// K2: gate[b,e,l] = att[l]/sum_l att[l], att[l]=sum_h e_att
__global__ void k_gate(const float* __restrict__ e_att, float* __restrict__ gate) {
    int be = blockIdx.x;
    __shared__ float att_s[LL];
    __shared__ float red[4];
    const float* ea = e_att + (size_t)be * NHH * LL;
    float lsum = 0.f;
    for (int l = threadIdx.x; l < LL; l += blockDim.x) {
        float a = 0.f;
        for (int h = 0; h < NHH; h++) a += ea[h * LL + l];
        att_s[l] = a;
        lsum += a;
    }
    for (int off = 32; off; off >>= 1) lsum += __shfl_down(lsum, off, 64);
    if ((threadIdx.x & 63) == 0) red[threadIdx.x >> 6] = lsum;
    __syncthreads();
    float inv = 1.f / (red[0] + red[1] + red[2] + red[3]);
    for (int l = threadIdx.x; l < LL; l += blockDim.x)
        gate[(size_t)be * LL + l] = att_s[l] * inv;
}

// K3: e_emb[b,e,d] = logsumexp over {3 mention embeds, 2 coref embeds}
__global__ void k_eemb(const float* __restrict__ seq, const float* __restrict__ gate,
                       const int* __restrict__ ms, const int* __restrict__ cs,
                       float* __restrict__ e_emb) {
    int be = blockIdx.x;
    int b = be / NEE;
    int p0 = ms[be * MMM + 0] + 1, p1 = ms[be * MMM + 1] + 1, p2 = ms[be * MMM + 2] + 1;
    int c0 = cs[be * NCC + 0], c1 = cs[be * NCC + 1];
    for (int d = threadIdx.x; d < HH; d += blockDim.x) {
        float v0 = seq[((size_t)b * LL + p0) * HH + d];
        float v1 = seq[((size_t)b * LL + p1) * HH + d];
        float v2 = seq[((size_t)b * LL + p2) * HH + d];
        float s0 = 0.f, s1 = 0.f;
        for (int w = 0; w < CWW; w++) {
            s0 += gate[(size_t)be * LL + c0 + w] * seq[((size_t)b * LL + c0 + w) * HH + d];
            s1 += gate[(size_t)be * LL + c1 + w] * seq[((size_t)b * LL + c1 + w) * HH + d];
        }
        float mx = fmaxf(fmaxf(fmaxf(v0, v1), fmaxf(v2, s0)), s1);
        float s = expf(v0 - mx) + expf(v1 - mx) + expf(v2 - mx) + expf(s0 - mx) + expf(s1 - mx);
        e_emb[(size_t)be * HH + d] = logf(s) + mx;
    }
}

// K4: ht[b,e,f,l] = relu(sum_h e_att[b,e,h,l]*e_att[b,f,h,l]) normalized over l
__global__ void k_ht(const float* __restrict__ e_att, float* __restrict__ ht) {
    int blk = blockIdx.x;   // ((b*NEE+e)*NEE+f)
    int f = blk % NEE;
    int e = (blk / NEE) % NEE;
    int b = blk / (NEE * NEE);
    const float* ea = e_att + (size_t)(b * NEE + e) * NHH * LL;
    const float* fa = e_att + (size_t)(b * NEE + f) * NHH * LL;
    __shared__ float hts[LL];
    __shared__ float red[4];
    float lsum = 0.f;
    for (int l = threadIdx.x; l < LL; l += blockDim.x) {
        float s = 0.f;
        for (int h = 0; h < NHH; h++) s += ea[h * LL + l] * fa[h * LL + l];
        s = fmaxf(s, 0.f);
        hts[l] = s;
        lsum += s;
    }
    for (int off = 32; off; off >>= 1) lsum += __shfl_down(lsum, off, 64);
    if ((threadIdx.x & 63) == 0) red[threadIdx.x >> 6] = lsum;
    __syncthreads();
    float inv = 1.f / (red[0] + red[1] + red[2] + red[3] + 1e-10f);
    for (int l = threadIdx.x; l < LL; l += blockDim.x)
        ht[(size_t)blk * LL + l] = hts[l] * inv;
}

// K5: rs[b,e,f,d] = sum_l ht[b,e,f,l]*seq[b,l,d]; block=(be, d-chunk), 24 f's per block
__global__ void k_rs(const float* __restrict__ seq, const float* __restrict__ ht,
                     float* __restrict__ rs) {
    int be = blockIdx.x;
    int b = be / NEE;
    int d = blockIdx.y * 256 + threadIdx.x;
    __shared__ float hl[NEE][256];
    float acc[NEE];
#pragma unroll
    for (int f = 0; f < NEE; f++) acc[f] = 0.f;
    for (int lc = 0; lc < LL; lc += 256) {
        __syncthreads();
        for (int idx = threadIdx.x; idx < NEE * 256; idx += 256) {
            int f = idx >> 8, l = idx & 255;
            hl[f][l] = ht[((size_t)be * NEE + f) * LL + lc + l];
        }
        __syncthreads();
        for (int l = 0; l < 256; l++) {
            float sv = seq[((size_t)b * LL + lc + l) * HH + d];
#pragma unroll
            for (int f = 0; f < NEE; f++) acc[f] += hl[f][l] * sv;
        }
    }
    for (int f = 0; f < NEE; f++)
        rs[((size_t)be * NEE + f) * HH + d] = acc[f];
}

// K6a: hsW[be,d] = sum_j e_emb[be,j]*W_head[d,j] ; tsW with W_tail (first HH cols)
__global__ void k_hw(const float* __restrict__ e_emb, const float* __restrict__ Wh,
                     const float* __restrict__ Wt, float* __restrict__ hsW,
                     float* __restrict__ tsW) {
    int m2 = blockIdx.x;
    int which = blockIdx.y;
    const float* Wm = which ? Wt : Wh;
    float* out = which ? tsW : hsW;
    const float* x = e_emb + (size_t)m2 * HH;
    int lane = threadIdx.x & 63, wv = threadIdx.x >> 6;
    for (int d = wv; d < HH; d += 4) {
        const float* wr = Wm + (size_t)d * (2 * HH);
        float s = 0.f;
        for (int j = lane; j < HH; j += 64) s += x[j] * wr[j];
        for (int off = 32; off; off >>= 1) s += __shfl_down(s, off, 64);
        if (lane == 0) out[(size_t)m2 * HH + d] = s;
    }
}

// K6b: rsW[m,n] = sum_k rs[m,k] * W2[n,k], W2 = [W_head[:,768:]; W_tail[:,768:]]
// NT GEMM, 64x64 tile, 4x4 microtile
__global__ void k_rsw(const float* __restrict__ rs, const float* __restrict__ Wh,
                      const float* __restrict__ Wt, float* __restrict__ rsW) {
    int m0 = blockIdx.x * 64, n0 = blockIdx.y * 64;
    __shared__ float As[16][68], Bs[16][68];
    int tx = threadIdx.x & 15, ty = threadIdx.x >> 4;
    int lr = threadIdx.x >> 2;          // 0..63
    int lk = (threadIdx.x & 3) * 4;     // 0,4,8,12
    float acc[4][4] = {};
    int n = n0 + lr;
    const float* brow = (n < HH) ? (Wh + (size_t)n * (2 * HH) + HH)
                                 : (Wt + (size_t)(n - HH) * (2 * HH) + HH);
    const float* arow = rs + (size_t)(m0 + lr) * HH;
    for (int k0 = 0; k0 < HH; k0 += 16) {
        float4 av = *(const float4*)(arow + k0 + lk);
        float4 bv = *(const float4*)(brow + k0 + lk);
        __syncthreads();
        As[lk + 0][lr] = av.x; As[lk + 1][lr] = av.y; As[lk + 2][lr] = av.z; As[lk + 3][lr] = av.w;
        Bs[lk + 0][lr] = bv.x; Bs[lk + 1][lr] = bv.y; Bs[lk + 2][lr] = bv.z; Bs[lk + 3][lr] = bv.w;
        __syncthreads();
#pragma unroll
        for (int kk = 0; kk < 16; kk++) {
            float a0 = As[kk][ty * 4 + 0], a1 = As[kk][ty * 4 + 1];
            float a2 = As[kk][ty * 4 + 2], a3 = As[kk][ty * 4 + 3];
            float b0 = Bs[kk][tx * 4 + 0], b1 = Bs[kk][tx * 4 + 1];
            float b2 = Bs[kk][tx * 4 + 2], b3 = Bs[kk][tx * 4 + 3];
            acc[0][0] += a0 * b0; acc[0][1] += a0 * b1; acc[0][2] += a0 * b2; acc[0][3] += a0 * b3;
            acc[1][0] += a1 * b0; acc[1][1] += a1 * b1; acc[1][2] += a1 * b2; acc[1][3] += a1 * b3;
            acc[2][0] += a2 * b0; acc[2][1] += a2 * b1; acc[2][2] += a2 * b2; acc[2][3] += a2 * b3;
            acc[3][0] += a3 * b0; acc[3][1] += a3 * b1; acc[3][2] += a3 * b2; acc[3][3] += a3 * b3;
        }
    }
#pragma unroll
    for (int i = 0; i < 4; i++)
#pragma unroll
        for (int j = 0; j < 4; j++)
            rsW[(size_t)(m0 + ty * 4 + i) * (2 * HH) + n0 + tx * 4 + j] = acc[i][j];
}

// K7: zh/zt = tanh(rsW + hsW/tsW + bias), in place.  hs uses e_emb[b,e], ts uses e_emb[b,f]
__global__ void k_tanh(float* __restrict__ rsW, const float* __restrict__ hsW,
                       const float* __restrict__ tsW, const float* __restrict__ bh,
                       const float* __restrict__ bt) {
    size_t i = (size_t)blockIdx.x * 256 + threadIdx.x;
    if (i >= (size_t)NEF * 2 * HH) return;
    int nn = (int)(i % (2 * HH));
    int m = (int)(i / (2 * HH));
    int f = m % NEE;
    int e = (m / NEE) % NEE;
    int b = m / (NEE * NEE);
    float v = rsW[i];
    if (nn < HH) v = tanhf(v + hsW[(size_t)(b * NEE + e) * HH + nn] + bh[nn]);
    else {
        int d = nn - HH;
        v = tanhf(v + tsW[(size_t)(b * NEE + f) * HH + d] + bt[d]);
    }
    rsW[i] = v;
}

// K8: WfT[n, c] = sum_k W_cls[c,k] * W_proj[k,n]   (c padded to NCP with zeros)
__global__ void k_wf(const float* __restrict__ Wp, const float* __restrict__ Wc,
                     float* __restrict__ WfT) {
    int n0 = blockIdx.x * 128;
    int lane = threadIdx.x & 63, quad = threadIdx.x >> 6;
    __shared__ float wcs[64][NCP + 1];
    float acc1[32] = {}, acc2[32] = {};
    int na = n0 + lane, nb = n0 + 64 + lane;
    for (int k0 = 0; k0 < HH; k0 += 64) {
        __syncthreads();
        for (int idx = threadIdx.x; idx < 64 * NCP; idx += 256) {
            int c = idx >> 6, k = idx & 63;
            wcs[k][c] = (c < NCLS) ? Wc[(size_t)c * HH + k0 + k] : 0.f;
        }
        __syncthreads();
        for (int k = 0; k < 64; k++) {
            float w1 = Wp[(size_t)(k0 + k) * HB + na];
            float w2 = Wp[(size_t)(k0 + k) * HB + nb];
#pragma unroll
            for (int cc = 0; cc < 32; cc++) {
                float lv = wcs[k][quad * 32 + cc];
                acc1[cc] += lv * w1;
                acc2[cc] += lv * w2;
            }
        }
    }
#pragma unroll
    for (int cc = 0; cc < 32; cc++) {
        WfT[(size_t)na * NCP + quad * 32 + cc] = acc1[cc];
        WfT[(size_t)nb * NCP + quad * 32 + cc] = acc2[cc];
    }
}

// K9a: out init with b_cls
__global__ void k_init(float* __restrict__ out, const float* __restrict__ bc) {
    int i = blockIdx.x * 256 + threadIdx.x;
    if (i < NEF * NCLS) out[i] = bc[i % NCLS];
}

// K9: logits[m,c] += sum_kk bl[m,kk]*WfT[kk,c]; bl on the fly from zh/zt.
// grid (NEF/32, KB); k-split partial sums accumulated via atomicAdd.
__global__ void k_logits(const float* __restrict__ zz, const float* __restrict__ WfT,
                         float* __restrict__ out) {
    int m0 = blockIdx.x * 32;
    int k = blockIdx.y;
    int c = threadIdx.x;    // 128 threads
    __shared__ float zhs[32][64], zts[32][64];
    for (int idx = threadIdx.x; idx < 32 * 64; idx += 128) {
        int mi = idx >> 6, i = idx & 63;
        zhs[mi][i] = zz[(size_t)(m0 + mi) * (2 * HH) + k * 64 + i];
        zts[mi][i] = zz[(size_t)(m0 + mi) * (2 * HH) + HH + k * 64 + i];
    }
    __syncthreads();
    float acc[32] = {};
    for (int i = 0; i < 64; i++) {
        float a[32];
#pragma unroll
        for (int mi = 0; mi < 32; mi++) a[mi] = zhs[mi][i];
        const float* wp = WfT + ((size_t)k * 4096 + i * 64) * NCP + c;
        for (int j = 0; j < 64; j++) {
            float wf = wp[(size_t)j * NCP];
#pragma unroll
            for (int mi = 0; mi < 32; mi++)
                acc[mi] += a[mi] * zts[mi][j] * wf;
        }
    }
    if (c < NCLS) {
        for (int mi = 0; mi < 32; mi++)
            atomicAdd(&out[(size_t)(m0 + mi) * NCLS + c], acc[mi]);
    }
}

// ---------------------------------------------------------------------------
extern "C" void kernel_launch(void* const* d_in, const int* in_sizes, int n_in,
                              void* d_out, int out_size, void* d_ws, size_t ws_size,
                              hipStream_t stream) {
    const float* seq  = (const float*)d_in[0];
    const float* attn = (const float*)d_in[1];
    const int*   ms   = (const int*)d_in[2];
    const int*   cs   = (const int*)d_in[3];
    const float* Wh   = (const float*)d_in[4];
    const float* bh   = (const float*)d_in[5];
    const float* Wt   = (const float*)d_in[6];
    const float* bt   = (const float*)d_in[7];
    const float* Wp   = (const float*)d_in[8];
    const float* Wc   = (const float*)d_in[9];
    const float* bc   = (const float*)d_in[10];
    float* out = (float*)d_out;

    // Workspace layout (floats). WfT overlaps the gather scratch (dead by then).
    // Total 8060928 floats = 32.2 MB.
    float* w     = (float*)d_ws;
    float* rsW   = w;                        // 1769472  (zh|zt after k_tanh)
    float* e_att = rsW + 1769472;            // 589824
    float* gate  = e_att + 589824;           // 49152
    float* ht    = gate + 49152;             // 1179648
    float* rs    = ht + 1179648;             // 884736
    float* eemb  = rs + 884736;              // 36864
    float* hsW   = eemb + 36864;             // 36864
    float* tsW   = hsW + 36864;              // 36864
    float* WfT   = rsW + 1769472;            // 6291456, overlaps e_att..tsW (written after)

    k_eatt<<<BB * NEE * NHH, 256, 0, stream>>>(attn, ms, e_att);
    k_gate<<<BB * NEE, 256, 0, stream>>>(e_att, gate);
    k_eemb<<<BB * NEE, 256, 0, stream>>>(seq, gate, ms, cs, eemb);
    k_ht<<<NEF, 256, 0, stream>>>(e_att, ht);
    k_rs<<<dim3(BB * NEE, 3), 256, 0, stream>>>(seq, ht, rs);
    k_hw<<<dim3(BB * NEE, 2), 256, 0, stream>>>(eemb, Wh, Wt, hsW, tsW);
    k_rsw<<<dim3(NEF / 64, 2 * HH / 64), 256, 0, stream>>>(rs, Wh, Wt, rsW);
    k_tanh<<<(NEF * 2 * HH + 255) / 256, 256, 0, stream>>>(rsW, hsW, tsW, bh, bt);
    k_init<<<(NEF * NCLS + 255) / 256, 256, 0, stream>>>(out, bc);
    k_wf<<<HB / 128, 256, 0, stream>>>(Wp, Wc, WfT);
    k_logits<<<dim3(NEF / 32, KB), 128, 0, stream>>>(rsW, WfT, out);
}

// Round 2
// 1820.348 us; speedup vs baseline: 1.9349x; 1.9349x over previous
//
#include <hip/hip_runtime.h>
#include <math.h>

// Problem constants
#define BB   2
#define LL   1024
#define HH   768
#define NHH  12
#define NEE  24
#define MMM  3
#define NCC  2
#define CWW  8
#define BLK  64
#define NCLS 97
#define KB   12          // HH/BLK
#define HB   49152       // HH*BLK
#define NCP  128         // padded class dim for Wf
#define NEF  1152        // BB*NEE*NEE

typedef unsigned int uint;
typedef unsigned short ushort;
typedef __attribute__((ext_vector_type(8))) short bf16x8;
typedef __attribute__((ext_vector_type(4))) float f32x4;

// round-to-nearest-even fp32 -> bf16
__device__ __forceinline__ ushort f2bf(float f) {
    uint u = __float_as_uint(f);
    u += 0x7fffu + ((u >> 16) & 1u);
    return (ushort)(u >> 16);
}

// ---------------------------------------------------------------------------
// K1: e_att[b,e,h,l] = mean_m attention[b,h,ms[b,e,m]+1,l]
__global__ void k_eatt(const float* __restrict__ att_in, const int* __restrict__ ms,
                       float* __restrict__ e_att) {
    int blk = blockIdx.x;               // (b*NEE+e)*NHH + h
    int h = blk % NHH;
    int e = (blk / NHH) % NEE;
    int b = blk / (NHH * NEE);
    int base = (b * NEE + e) * MMM;
    int p0 = ms[base + 0] + 1;
    int p1 = ms[base + 1] + 1;
    int p2 = ms[base + 2] + 1;
    const float* r0 = att_in + ((size_t)(b * NHH + h) * LL + p0) * LL;
    const float* r1 = att_in + ((size_t)(b * NHH + h) * LL + p1) * LL;
    const float* r2 = att_in + ((size_t)(b * NHH + h) * LL + p2) * LL;
    float* o = e_att + ((size_t)(b * NEE + e) * NHH + h) * LL;
    for (int l = threadIdx.x; l < LL; l += blockDim.x)
        o[l] = (r0[l] + r1[l] + r2[l]) * (1.f / 3.f);
}

// K2: gate[b,e,l] = att[l]/sum_l att[l], att[l]=sum_h e_att
__global__ void k_gate(const float* __restrict__ e_att, float* __restrict__ gate) {
    int be = blockIdx.x;
    __shared__ float att_s[LL];
    __shared__ float red[4];
    const float* ea = e_att + (size_t)be * NHH * LL;
    float lsum = 0.f;
    for (int l = threadIdx.x; l < LL; l += blockDim.x) {
        float a = 0.f;
        for (int h = 0; h < NHH; h++) a += ea[h * LL + l];
        att_s[l] = a;
        lsum += a;
    }
    for (int off = 32; off; off >>= 1) lsum += __shfl_down(lsum, off, 64);
    if ((threadIdx.x & 63) == 0) red[threadIdx.x >> 6] = lsum;
    __syncthreads();
    float inv = 1.f / (red[0] + red[1] + red[2] + red[3]);
    for (int l = threadIdx.x; l < LL; l += blockDim.x)
        gate[(size_t)be * LL + l] = att_s[l] * inv;
}

// K3: e_emb[b,e,d] = logsumexp over {3 mention embeds, 2 coref embeds}
__global__ void k_eemb(const float* __restrict__ seq, const float* __restrict__ gate,
                       const int* __restrict__ ms, const int* __restrict__ cs,
                       float* __restrict__ e_emb) {
    int be = blockIdx.x;
    int b = be / NEE;
    int p0 = ms[be * MMM + 0] + 1, p1 = ms[be * MMM + 1] + 1, p2 = ms[be * MMM + 2] + 1;
    int c0 = cs[be * NCC + 0], c1 = cs[be * NCC + 1];
    for (int d = threadIdx.x; d < HH; d += blockDim.x) {
        float v0 = seq[((size_t)b * LL + p0) * HH + d];
        float v1 = seq[((size_t)b * LL + p1) * HH + d];
        float v2 = seq[((size_t)b * LL + p2) * HH + d];
        float s0 = 0.f, s1 = 0.f;
        for (int w = 0; w < CWW; w++) {
            s0 += gate[(size_t)be * LL + c0 + w] * seq[((size_t)b * LL + c0 + w) * HH + d];
            s1 += gate[(size_t)be * LL + c1 + w] * seq[((size_t)b * LL + c1 + w) * HH + d];
        }
        float mx = fmaxf(fmaxf(fmaxf(v0, v1), fmaxf(v2, s0)), s1);
        float s = expf(v0 - mx) + expf(v1 - mx) + expf(v2 - mx) + expf(s0 - mx) + expf(s1 - mx);
        e_emb[(size_t)be * HH + d] = logf(s) + mx;
    }
}

// K4: ht[b,e,f,l] = relu(sum_h e_att[b,e,h,l]*e_att[b,f,h,l]) normalized over l
__global__ void k_ht(const float* __restrict__ e_att, float* __restrict__ ht) {
    int blk = blockIdx.x;   // ((b*NEE+e)*NEE+f)
    int f = blk % NEE;
    int e = (blk / NEE) % NEE;
    int b = blk / (NEE * NEE);
    const float* ea = e_att + (size_t)(b * NEE + e) * NHH * LL;
    const float* fa = e_att + (size_t)(b * NEE + f) * NHH * LL;
    __shared__ float hts[LL];
    __shared__ float red[4];
    float lsum = 0.f;
    for (int l = threadIdx.x; l < LL; l += blockDim.x) {
        float s = 0.f;
        for (int h = 0; h < NHH; h++) s += ea[h * LL + l] * fa[h * LL + l];
        s = fmaxf(s, 0.f);
        hts[l] = s;
        lsum += s;
    }
    for (int off = 32; off; off >>= 1) lsum += __shfl_down(lsum, off, 64);
    if ((threadIdx.x & 63) == 0) red[threadIdx.x >> 6] = lsum;
    __syncthreads();
    float inv = 1.f / (red[0] + red[1] + red[2] + red[3] + 1e-10f);
    for (int l = threadIdx.x; l < LL; l += blockDim.x)
        ht[(size_t)blk * LL + l] = hts[l] * inv;
}

// K5: rs[b,e,f,d] = sum_l ht[b,e,f,l]*seq[b,l,d]
__global__ void k_rs(const float* __restrict__ seq, const float* __restrict__ ht,
                     float* __restrict__ rs) {
    int be = blockIdx.x;
    int b = be / NEE;
    int d = blockIdx.y * 256 + threadIdx.x;
    __shared__ float hl[NEE][256];
    float acc[NEE];
#pragma unroll
    for (int f = 0; f < NEE; f++) acc[f] = 0.f;
    for (int lc = 0; lc < LL; lc += 256) {
        __syncthreads();
        for (int idx = threadIdx.x; idx < NEE * 256; idx += 256) {
            int f = idx >> 8, l = idx & 255;
            hl[f][l] = ht[((size_t)be * NEE + f) * LL + lc + l];
        }
        __syncthreads();
        for (int l = 0; l < 256; l++) {
            float sv = seq[((size_t)b * LL + lc + l) * HH + d];
#pragma unroll
            for (int f = 0; f < NEE; f++) acc[f] += hl[f][l] * sv;
        }
    }
    for (int f = 0; f < NEE; f++)
        rs[((size_t)be * NEE + f) * HH + d] = acc[f];
}

// K6a: hsW[be,d] = sum_j e_emb[be,j]*W_head[d,j] ; tsW with W_tail (first HH cols)
__global__ void k_hw(const float* __restrict__ e_emb, const float* __restrict__ Wh,
                     const float* __restrict__ Wt, float* __restrict__ hsW,
                     float* __restrict__ tsW) {
    int m2 = blockIdx.x;
    int which = blockIdx.y;
    const float* Wm = which ? Wt : Wh;
    float* out = which ? tsW : hsW;
    const float* x = e_emb + (size_t)m2 * HH;
    int lane = threadIdx.x & 63, wv = threadIdx.x >> 6;
    for (int d = wv; d < HH; d += 4) {
        const float* wr = Wm + (size_t)d * (2 * HH);
        float s = 0.f;
        for (int j = lane; j < HH; j += 64) s += x[j] * wr[j];
        for (int off = 32; off; off >>= 1) s += __shfl_down(s, off, 64);
        if (lane == 0) out[(size_t)m2 * HH + d] = s;
    }
}

// K6b: rsW[m,n] = sum_k rs[m,k] * W2[n,k], W2 = [W_head[:,768:]; W_tail[:,768:]]
__global__ void k_rsw(const float* __restrict__ rs, const float* __restrict__ Wh,
                      const float* __restrict__ Wt, float* __restrict__ rsW) {
    int m0 = blockIdx.x * 64, n0 = blockIdx.y * 64;
    __shared__ float As[16][68], Bs[16][68];
    int tx = threadIdx.x & 15, ty = threadIdx.x >> 4;
    int lr = threadIdx.x >> 2;          // 0..63
    int lk = (threadIdx.x & 3) * 4;     // 0,4,8,12
    float acc[4][4] = {};
    int n = n0 + lr;
    const float* brow = (n < HH) ? (Wh + (size_t)n * (2 * HH) + HH)
                                 : (Wt + (size_t)(n - HH) * (2 * HH) + HH);
    const float* arow = rs + (size_t)(m0 + lr) * HH;
    for (int k0 = 0; k0 < HH; k0 += 16) {
        float4 av = *(const float4*)(arow + k0 + lk);
        float4 bv = *(const float4*)(brow + k0 + lk);
        __syncthreads();
        As[lk + 0][lr] = av.x; As[lk + 1][lr] = av.y; As[lk + 2][lr] = av.z; As[lk + 3][lr] = av.w;
        Bs[lk + 0][lr] = bv.x; Bs[lk + 1][lr] = bv.y; Bs[lk + 2][lr] = bv.z; Bs[lk + 3][lr] = bv.w;
        __syncthreads();
#pragma unroll
        for (int kk = 0; kk < 16; kk++) {
            float a0 = As[kk][ty * 4 + 0], a1 = As[kk][ty * 4 + 1];
            float a2 = As[kk][ty * 4 + 2], a3 = As[kk][ty * 4 + 3];
            float b0 = Bs[kk][tx * 4 + 0], b1 = Bs[kk][tx * 4 + 1];
            float b2 = Bs[kk][tx * 4 + 2], b3 = Bs[kk][tx * 4 + 3];
            acc[0][0] += a0 * b0; acc[0][1] += a0 * b1; acc[0][2] += a0 * b2; acc[0][3] += a0 * b3;
            acc[1][0] += a1 * b0; acc[1][1] += a1 * b1; acc[1][2] += a1 * b2; acc[1][3] += a1 * b3;
            acc[2][0] += a2 * b0; acc[2][1] += a2 * b1; acc[2][2] += a2 * b2; acc[2][3] += a2 * b3;
            acc[3][0] += a3 * b0; acc[3][1] += a3 * b1; acc[3][2] += a3 * b2; acc[3][3] += a3 * b3;
        }
    }
#pragma unroll
    for (int i = 0; i < 4; i++)
#pragma unroll
        for (int j = 0; j < 4; j++)
            rsW[(size_t)(m0 + ty * 4 + i) * (2 * HH) + n0 + tx * 4 + j] = acc[i][j];
}

// K7: zb = bf16(tanh(rsW + hsW/tsW + bias)).  hs uses e_emb[b,e], ts uses e_emb[b,f]
__global__ void k_tanh(const float* __restrict__ rsW, const float* __restrict__ hsW,
                       const float* __restrict__ tsW, const float* __restrict__ bh,
                       const float* __restrict__ bt, ushort* __restrict__ zb) {
    size_t i = (size_t)blockIdx.x * 256 + threadIdx.x;
    if (i >= (size_t)NEF * 2 * HH) return;
    int nn = (int)(i % (2 * HH));
    int m = (int)(i / (2 * HH));
    int f = m % NEE;
    int e = (m / NEE) % NEE;
    int b = m / (NEE * NEE);
    float v = rsW[i];
    if (nn < HH) v = tanhf(v + hsW[(size_t)(b * NEE + e) * HH + nn] + bh[nn]);
    else {
        int d = nn - HH;
        v = tanhf(v + tsW[(size_t)(b * NEE + f) * HH + d] + bt[d]);
    }
    zb[i] = f2bf(v);
}

// K8: Wf = W_cls @ W_proj packed bf16 in MFMA-B-fragment order:
// bpack[((n>>3)*NCP + c)*8 + (n&7)] = bf16(sum_k Wc[c,k]*Wp[k,n]); c>=NCLS -> 0
__global__ void k_wf(const float* __restrict__ Wp, const float* __restrict__ Wc,
                     ushort* __restrict__ bpack) {
    int n0 = blockIdx.x * 128;
    int lane = threadIdx.x & 63, quad = threadIdx.x >> 6;
    __shared__ float wcs[64][NCP + 1];
    float acc1[32] = {}, acc2[32] = {};
    int na = n0 + lane, nb = n0 + 64 + lane;
    for (int k0 = 0; k0 < HH; k0 += 64) {
        __syncthreads();
        for (int idx = threadIdx.x; idx < 64 * NCP; idx += 256) {
            int c = idx >> 6, k = idx & 63;
            wcs[k][c] = (c < NCLS) ? Wc[(size_t)c * HH + k0 + k] : 0.f;
        }
        __syncthreads();
        for (int k = 0; k < 64; k++) {
            float w1 = Wp[(size_t)(k0 + k) * HB + na];
            float w2 = Wp[(size_t)(k0 + k) * HB + nb];
#pragma unroll
            for (int cc = 0; cc < 32; cc++) {
                float lv = wcs[k][quad * 32 + cc];
                acc1[cc] += lv * w1;
                acc2[cc] += lv * w2;
            }
        }
    }
#pragma unroll
    for (int cc = 0; cc < 32; cc++) {
        int c = quad * 32 + cc;
        bpack[((size_t)(na >> 3) * NCP + c) * 8 + (na & 7)] = f2bf(acc1[cc]);
        bpack[((size_t)(nb >> 3) * NCP + c) * 8 + (nb & 7)] = f2bf(acc2[cc]);
    }
}

// K9a: out init with b_cls
__global__ void k_init(float* __restrict__ out, const float* __restrict__ bc) {
    int i = blockIdx.x * 256 + threadIdx.x;
    if (i < NEF * NCLS) out[i] = bc[i % NCLS];
}

// K9: MFMA logits. out[m,c] += sum over K-slice of bl[m,k]*Wf[c,k],
// bl generated on the fly in A-fragment layout from zh/zt LDS tiles.
// Grid (NEF/64, 24): M-tile 64, K-slice 2048, fp32 atomic accumulation.
#define ZTP 88
#define ZHP 48
__global__ __launch_bounds__(256, 2) void k_logits(const ushort* __restrict__ zb,
                                                   const ushort* __restrict__ bpack,
                                                   float* __restrict__ out) {
    __shared__ ushort zhs[64 * ZHP];
    __shared__ ushort zts[64 * ZTP];
    __shared__ ushort Bls[16384];   // 32 KB: one K=128 stage of B-fragments
    int m0 = blockIdx.x * 64;
    int kb = blockIdx.y;            // K-slice of 2048
    int kg = kb >> 1;               // which 4096-block (i*64+j space)
    int ihalf = (kb & 1) * 32;      // which half of the i range
    int tid = threadIdx.x;
    int lane = tid & 63, w = tid >> 6;
    int tt = lane >> 4, r16 = lane & 15;
    int wm = (w & 1) * 32, wn = (w >> 1) * 64;

    // zt tile: 64 rows x 64 cols (cols kg*64..+64 of the zt half)
    {
        int row = tid >> 2, c8 = (tid & 3) * 16;
        const ushort* src = zb + (size_t)(m0 + row) * 1536 + 768 + kg * 64 + c8;
        uint4 v0 = *(const uint4*)src;
        uint4 v1 = *(const uint4*)(src + 8);
        *(uint4*)&zts[row * ZTP + c8] = v0;
        *(uint4*)&zts[row * ZTP + c8 + 8] = v1;
    }
    // zh tile: 64 rows x 32 cols (cols kg*64+ihalf..+32 of the zh half)
    {
        int row = tid >> 2, c8 = (tid & 3) * 8;
        const ushort* src = zb + (size_t)(m0 + row) * 1536 + kg * 64 + ihalf + c8;
        *(uint4*)&zhs[row * ZHP + c8] = *(const uint4*)src;
    }

    f32x4 acc[2][4];
    f32x4 zero = {0.f, 0.f, 0.f, 0.f};
#pragma unroll
    for (int t = 0; t < 2; t++)
#pragma unroll
        for (int n = 0; n < 4; n++) acc[t][n] = zero;

    const char* bbase = (const char*)bpack + (size_t)kb * 2048 * 256; // kb*2048 k's * 256 B/k... (= kb*256 groups *2048B)
    for (int g = 0; g < 16; g++) {
        __syncthreads();
        const char* sb = bbase + (size_t)g * 32768;
#pragma unroll
        for (int q = 0; q < 8; q++) {
            int off = (q * 4 + w) * 1024;
            __builtin_amdgcn_global_load_lds(
                (const __attribute__((address_space(1))) void*)(sb + off + lane * 16),
                (__attribute__((address_space(3))) void*)((char*)Bls + off),
                16, 0, 0);
        }
        __syncthreads();
#pragma unroll
        for (int ks = 0; ks < 4; ks++) {
            int s = g * 4 + ks;
            int il = s >> 1;            // i within this slice's half
            int j0 = (s & 1) * 32;      // j chunk base
            bf16x8 af[2];
#pragma unroll
            for (int t = 0; t < 2; t++) {
                int row = wm + t * 16 + r16;
                float zhf = __uint_as_float((uint)zhs[row * ZHP + il] << 16);
                union { bf16x8 v; uint u[4]; } zt8, a;
                zt8.v = *(const bf16x8*)&zts[row * ZTP + j0 + tt * 8];
#pragma unroll
                for (int q = 0; q < 4; q++) {
                    uint p = zt8.u[q];
                    uint lo = __float_as_uint(__uint_as_float(p << 16) * zhf);
                    uint hi = __float_as_uint(__uint_as_float(p & 0xFFFF0000u) * zhf);
                    a.u[q] = (lo >> 16) | (hi & 0xFFFF0000u);   // truncate-to-bf16 pair
                }
                af[t] = a.v;
            }
#pragma unroll
            for (int n = 0; n < 4; n++) {
                bf16x8 bf = *(const bf16x8*)&Bls[(size_t)((ks * 4 + tt) * NCP + wn + n * 16 + r16) * 8];
                acc[0][n] = __builtin_amdgcn_mfma_f32_16x16x32_bf16(af[0], bf, acc[0][n], 0, 0, 0);
                acc[1][n] = __builtin_amdgcn_mfma_f32_16x16x32_bf16(af[1], bf, acc[1][n], 0, 0, 0);
            }
        }
    }
    // epilogue: C/D layout col=lane&15, row=(lane>>4)*4+reg   [m89-verified]
    int rbase = (lane >> 4) * 4;
#pragma unroll
    for (int t = 0; t < 2; t++)
#pragma unroll
        for (int n = 0; n < 4; n++) {
            int c = wn + n * 16 + r16;
            if (c < NCLS) {
                int row = m0 + wm + t * 16 + rbase;
#pragma unroll
                for (int r = 0; r < 4; r++)
                    atomicAdd(&out[(size_t)(row + r) * NCLS + c], acc[t][n][r]);
            }
        }
}

// ---------------------------------------------------------------------------
extern "C" void kernel_launch(void* const* d_in, const int* in_sizes, int n_in,
                              void* d_out, int out_size, void* d_ws, size_t ws_size,
                              hipStream_t stream) {
    const float* seq  = (const float*)d_in[0];
    const float* attn = (const float*)d_in[1];
    const int*   ms   = (const int*)d_in[2];
    const int*   cs   = (const int*)d_in[3];
    const float* Wh   = (const float*)d_in[4];
    const float* bh   = (const float*)d_in[5];
    const float* Wt   = (const float*)d_in[6];
    const float* bt   = (const float*)d_in[7];
    const float* Wp   = (const float*)d_in[8];
    const float* Wc   = (const float*)d_in[9];
    const float* bc   = (const float*)d_in[10];
    float* out = (float*)d_out;

    // Workspace (floats). Region B is reused: gather scratch dies after k_tanh,
    // then bpack (bf16 Wf) overlays it. zb sits past both live ranges.
    float* w     = (float*)d_ws;
    float* rsW   = w;                        // 1,769,472
    float* regB  = w + 1769472;
    float* e_att = regB;                     // 589,824
    float* gate  = e_att + 589824;           // 49,152
    float* ht    = gate + 49152;             // 1,179,648
    float* rs    = ht + 1179648;             // 884,736
    float* eemb  = rs + 884736;              // 36,864
    float* hsW   = eemb + 36864;             // 36,864
    float* tsW   = hsW + 36864;              // 36,864  (regB ends at +2,813,952)
    ushort* bpack = (ushort*)regB;           // 6,291,456 bf16 (overlays e_att..tsW, written after k_tanh)
    ushort* zb    = (ushort*)(regB + 3145728); // 1,769,472 bf16

    k_eatt<<<BB * NEE * NHH, 256, 0, stream>>>(attn, ms, e_att);
    k_gate<<<BB * NEE, 256, 0, stream>>>(e_att, gate);
    k_eemb<<<BB * NEE, 256, 0, stream>>>(seq, gate, ms, cs, eemb);
    k_ht<<<NEF, 256, 0, stream>>>(e_att, ht);
    k_rs<<<dim3(BB * NEE, 3), 256, 0, stream>>>(seq, ht, rs);
    k_hw<<<dim3(BB * NEE, 2), 256, 0, stream>>>(eemb, Wh, Wt, hsW, tsW);
    k_rsw<<<dim3(NEF / 64, 2 * HH / 64), 256, 0, stream>>>(rs, Wh, Wt, rsW);
    k_tanh<<<(NEF * 2 * HH + 255) / 256, 256, 0, stream>>>(rsW, hsW, tsW, bh, bt, zb);
    k_wf<<<HB / 128, 256, 0, stream>>>(Wp, Wc, bpack);     // after k_tanh: clobbers hsW/tsW region
    k_init<<<(NEF * NCLS + 255) / 256, 256, 0, stream>>>(out, bc);
    k_logits<<<dim3(NEF / 64, 24), 256, 0, stream>>>(zb, bpack, out);
}

// Round 3
// 987.768 us; speedup vs baseline: 3.5659x; 1.8429x over previous
//
#include <hip/hip_runtime.h>
#include <math.h>

// Problem constants
#define BB   2
#define LL   1024
#define HH   768
#define NHH  12
#define NEE  24
#define MMM  3
#define NCC  2
#define CWW  8
#define BLK  64
#define NCLS 97
#define KB   12          // HH/BLK
#define HB   49152       // HH*BLK
#define NCP  128         // padded class dim for Wf
#define NEF  1152        // BB*NEE*NEE

typedef unsigned int uint;
typedef unsigned short ushort;
typedef __attribute__((ext_vector_type(8))) short bf16x8;
typedef __attribute__((ext_vector_type(4))) float f32x4;

// round-to-nearest-even fp32 -> bf16
__device__ __forceinline__ ushort f2bf(float f) {
    uint u = __float_as_uint(f);
    u += 0x7fffu + ((u >> 16) & 1u);
    return (ushort)(u >> 16);
}

// ---------------------------------------------------------------------------
// K1: e_att[b,e,h,l] = mean_m attention[b,h,ms[b,e,m]+1,l]
__global__ void k_eatt(const float* __restrict__ att_in, const int* __restrict__ ms,
                       float* __restrict__ e_att) {
    int blk = blockIdx.x;               // (b*NEE+e)*NHH + h
    int h = blk % NHH;
    int e = (blk / NHH) % NEE;
    int b = blk / (NHH * NEE);
    int base = (b * NEE + e) * MMM;
    int p0 = ms[base + 0] + 1;
    int p1 = ms[base + 1] + 1;
    int p2 = ms[base + 2] + 1;
    const float* r0 = att_in + ((size_t)(b * NHH + h) * LL + p0) * LL;
    const float* r1 = att_in + ((size_t)(b * NHH + h) * LL + p1) * LL;
    const float* r2 = att_in + ((size_t)(b * NHH + h) * LL + p2) * LL;
    float* o = e_att + ((size_t)(b * NEE + e) * NHH + h) * LL;
    for (int l = threadIdx.x; l < LL; l += blockDim.x)
        o[l] = (r0[l] + r1[l] + r2[l]) * (1.f / 3.f);
}

// K2: gate[b,e,l] = att[l]/sum_l att[l], att[l]=sum_h e_att
__global__ void k_gate(const float* __restrict__ e_att, float* __restrict__ gate) {
    int be = blockIdx.x;
    __shared__ float att_s[LL];
    __shared__ float red[4];
    const float* ea = e_att + (size_t)be * NHH * LL;
    float lsum = 0.f;
    for (int l = threadIdx.x; l < LL; l += blockDim.x) {
        float a = 0.f;
        for (int h = 0; h < NHH; h++) a += ea[h * LL + l];
        att_s[l] = a;
        lsum += a;
    }
    for (int off = 32; off; off >>= 1) lsum += __shfl_down(lsum, off, 64);
    if ((threadIdx.x & 63) == 0) red[threadIdx.x >> 6] = lsum;
    __syncthreads();
    float inv = 1.f / (red[0] + red[1] + red[2] + red[3]);
    for (int l = threadIdx.x; l < LL; l += blockDim.x)
        gate[(size_t)be * LL + l] = att_s[l] * inv;
}

// K3: e_emb[b,e,d] = logsumexp over {3 mention embeds, 2 coref embeds}
__global__ void k_eemb(const float* __restrict__ seq, const float* __restrict__ gate,
                       const int* __restrict__ ms, const int* __restrict__ cs,
                       float* __restrict__ e_emb) {
    int be = blockIdx.x;
    int b = be / NEE;
    int p0 = ms[be * MMM + 0] + 1, p1 = ms[be * MMM + 1] + 1, p2 = ms[be * MMM + 2] + 1;
    int c0 = cs[be * NCC + 0], c1 = cs[be * NCC + 1];
    for (int d = threadIdx.x; d < HH; d += blockDim.x) {
        float v0 = seq[((size_t)b * LL + p0) * HH + d];
        float v1 = seq[((size_t)b * LL + p1) * HH + d];
        float v2 = seq[((size_t)b * LL + p2) * HH + d];
        float s0 = 0.f, s1 = 0.f;
        for (int w = 0; w < CWW; w++) {
            s0 += gate[(size_t)be * LL + c0 + w] * seq[((size_t)b * LL + c0 + w) * HH + d];
            s1 += gate[(size_t)be * LL + c1 + w] * seq[((size_t)b * LL + c1 + w) * HH + d];
        }
        float mx = fmaxf(fmaxf(fmaxf(v0, v1), fmaxf(v2, s0)), s1);
        float s = expf(v0 - mx) + expf(v1 - mx) + expf(v2 - mx) + expf(s0 - mx) + expf(s1 - mx);
        e_emb[(size_t)be * HH + d] = logf(s) + mx;
    }
}

// K4: ht[b,e,f,l] = relu(sum_h e_att[b,e,h,l]*e_att[b,f,h,l]) normalized over l
__global__ void k_ht(const float* __restrict__ e_att, float* __restrict__ ht) {
    int blk = blockIdx.x;   // ((b*NEE+e)*NEE+f)
    int f = blk % NEE;
    int e = (blk / NEE) % NEE;
    int b = blk / (NEE * NEE);
    const float* ea = e_att + (size_t)(b * NEE + e) * NHH * LL;
    const float* fa = e_att + (size_t)(b * NEE + f) * NHH * LL;
    __shared__ float hts[LL];
    __shared__ float red[4];
    float lsum = 0.f;
    for (int l = threadIdx.x; l < LL; l += blockDim.x) {
        float s = 0.f;
        for (int h = 0; h < NHH; h++) s += ea[h * LL + l] * fa[h * LL + l];
        s = fmaxf(s, 0.f);
        hts[l] = s;
        lsum += s;
    }
    for (int off = 32; off; off >>= 1) lsum += __shfl_down(lsum, off, 64);
    if ((threadIdx.x & 63) == 0) red[threadIdx.x >> 6] = lsum;
    __syncthreads();
    float inv = 1.f / (red[0] + red[1] + red[2] + red[3] + 1e-10f);
    for (int l = threadIdx.x; l < LL; l += blockDim.x)
        ht[(size_t)blk * LL + l] = hts[l] * inv;
}

// K5: rs[b,e,f,d] = sum_l ht[b,e,f,l]*seq[b,l,d]
__global__ void k_rs(const float* __restrict__ seq, const float* __restrict__ ht,
                     float* __restrict__ rs) {
    int be = blockIdx.x;
    int b = be / NEE;
    int d = blockIdx.y * 256 + threadIdx.x;
    __shared__ float hl[NEE][256];
    float acc[NEE];
#pragma unroll
    for (int f = 0; f < NEE; f++) acc[f] = 0.f;
    for (int lc = 0; lc < LL; lc += 256) {
        __syncthreads();
        for (int idx = threadIdx.x; idx < NEE * 256; idx += 256) {
            int f = idx >> 8, l = idx & 255;
            hl[f][l] = ht[((size_t)be * NEE + f) * LL + lc + l];
        }
        __syncthreads();
        for (int l = 0; l < 256; l++) {
            float sv = seq[((size_t)b * LL + lc + l) * HH + d];
#pragma unroll
            for (int f = 0; f < NEE; f++) acc[f] += hl[f][l] * sv;
        }
    }
    for (int f = 0; f < NEE; f++)
        rs[((size_t)be * NEE + f) * HH + d] = acc[f];
}

// K6a: hsW[m2,d] = sum_j e_emb[m2,j]*Wm[d,j] (first HH cols of Wh/Wt).
// Latency fix (R2): grid (48,2,12) = 1152 blocks; x staged in LDS; each wave
// does 16 d's with per-lane 12-elem partial + shuffle reduce. Was 96 blocks
// with 192 serial chained dots/wave -> 848 us at 1% VALUBusy.
__global__ void k_hw(const float* __restrict__ e_emb, const float* __restrict__ Wh,
                     const float* __restrict__ Wt, float* __restrict__ hsW,
                     float* __restrict__ tsW) {
    int m2 = blockIdx.x;          // 0..47
    int which = blockIdx.y;       // 0..1
    int chunk = blockIdx.z;       // 0..11 (64 d's each)
    const float* Wm = which ? Wt : Wh;
    float* outp = which ? tsW : hsW;
    __shared__ float xs[HH];
    const float* x = e_emb + (size_t)m2 * HH;
    for (int j = threadIdx.x; j < HH; j += 256) xs[j] = x[j];
    __syncthreads();
    int lane = threadIdx.x & 63, w = threadIdx.x >> 6;
    int d0 = chunk * 64 + w * 16;
#pragma unroll 4
    for (int i = 0; i < 16; i++) {
        int d = d0 + i;
        const float* wr = Wm + (size_t)d * (2 * HH);
        float s = 0.f;
#pragma unroll
        for (int jj = 0; jj < 12; jj++) s += xs[lane + jj * 64] * wr[lane + jj * 64];
        for (int off = 32; off; off >>= 1) s += __shfl_down(s, off, 64);
        if (lane == 0) outp[(size_t)m2 * HH + d] = s;
    }
}

// K6b: rsW[m,n] = sum_k rs[m,k] * W2[n,k], W2 = [W_head[:,768:]; W_tail[:,768:]]
__global__ void k_rsw(const float* __restrict__ rs, const float* __restrict__ Wh,
                      const float* __restrict__ Wt, float* __restrict__ rsW) {
    int m0 = blockIdx.x * 64, n0 = blockIdx.y * 64;
    __shared__ float As[16][68], Bs[16][68];
    int tx = threadIdx.x & 15, ty = threadIdx.x >> 4;
    int lr = threadIdx.x >> 2;          // 0..63
    int lk = (threadIdx.x & 3) * 4;     // 0,4,8,12
    float acc[4][4] = {};
    int n = n0 + lr;
    const float* brow = (n < HH) ? (Wh + (size_t)n * (2 * HH) + HH)
                                 : (Wt + (size_t)(n - HH) * (2 * HH) + HH);
    const float* arow = rs + (size_t)(m0 + lr) * HH;
    for (int k0 = 0; k0 < HH; k0 += 16) {
        float4 av = *(const float4*)(arow + k0 + lk);
        float4 bv = *(const float4*)(brow + k0 + lk);
        __syncthreads();
        As[lk + 0][lr] = av.x; As[lk + 1][lr] = av.y; As[lk + 2][lr] = av.z; As[lk + 3][lr] = av.w;
        Bs[lk + 0][lr] = bv.x; Bs[lk + 1][lr] = bv.y; Bs[lk + 2][lr] = bv.z; Bs[lk + 3][lr] = bv.w;
        __syncthreads();
#pragma unroll
        for (int kk = 0; kk < 16; kk++) {
            float a0 = As[kk][ty * 4 + 0], a1 = As[kk][ty * 4 + 1];
            float a2 = As[kk][ty * 4 + 2], a3 = As[kk][ty * 4 + 3];
            float b0 = Bs[kk][tx * 4 + 0], b1 = Bs[kk][tx * 4 + 1];
            float b2 = Bs[kk][tx * 4 + 2], b3 = Bs[kk][tx * 4 + 3];
            acc[0][0] += a0 * b0; acc[0][1] += a0 * b1; acc[0][2] += a0 * b2; acc[0][3] += a0 * b3;
            acc[1][0] += a1 * b0; acc[1][1] += a1 * b1; acc[1][2] += a1 * b2; acc[1][3] += a1 * b3;
            acc[2][0] += a2 * b0; acc[2][1] += a2 * b1; acc[2][2] += a2 * b2; acc[2][3] += a2 * b3;
            acc[3][0] += a3 * b0; acc[3][1] += a3 * b1; acc[3][2] += a3 * b2; acc[3][3] += a3 * b3;
        }
    }
#pragma unroll
    for (int i = 0; i < 4; i++)
#pragma unroll
        for (int j = 0; j < 4; j++)
            rsW[(size_t)(m0 + ty * 4 + i) * (2 * HH) + n0 + tx * 4 + j] = acc[i][j];
}

// K7: zb = bf16(tanh(rsW + hsW/tsW + bias)).  hs uses e_emb[b,e], ts uses e_emb[b,f]
__global__ void k_tanh(const float* __restrict__ rsW, const float* __restrict__ hsW,
                       const float* __restrict__ tsW, const float* __restrict__ bh,
                       const float* __restrict__ bt, ushort* __restrict__ zb) {
    size_t i = (size_t)blockIdx.x * 256 + threadIdx.x;
    if (i >= (size_t)NEF * 2 * HH) return;
    int nn = (int)(i % (2 * HH));
    int m = (int)(i / (2 * HH));
    int f = m % NEE;
    int e = (m / NEE) % NEE;
    int b = m / (NEE * NEE);
    float v = rsW[i];
    if (nn < HH) v = tanhf(v + hsW[(size_t)(b * NEE + e) * HH + nn] + bh[nn]);
    else {
        int d = nn - HH;
        v = tanhf(v + tsW[(size_t)(b * NEE + f) * HH + d] + bt[d]);
    }
    zb[i] = f2bf(v);
}

// K8: Wf = W_cls @ W_proj packed bf16 in MFMA-B-fragment order:
// bpack[((n>>3)*NCP + c)*8 + (n&7)] = bf16(sum_k Wc[c,k]*Wp[k,n]); c>=NCLS -> 0
__global__ void k_wf(const float* __restrict__ Wp, const float* __restrict__ Wc,
                     ushort* __restrict__ bpack) {
    int n0 = blockIdx.x * 128;
    int lane = threadIdx.x & 63, quad = threadIdx.x >> 6;
    __shared__ float wcs[64][NCP + 1];
    float acc1[32] = {}, acc2[32] = {};
    int na = n0 + lane, nb = n0 + 64 + lane;
    for (int k0 = 0; k0 < HH; k0 += 64) {
        __syncthreads();
        for (int idx = threadIdx.x; idx < 64 * NCP; idx += 256) {
            int c = idx >> 6, k = idx & 63;
            wcs[k][c] = (c < NCLS) ? Wc[(size_t)c * HH + k0 + k] : 0.f;
        }
        __syncthreads();
        for (int k = 0; k < 64; k++) {
            float w1 = Wp[(size_t)(k0 + k) * HB + na];
            float w2 = Wp[(size_t)(k0 + k) * HB + nb];
#pragma unroll
            for (int cc = 0; cc < 32; cc++) {
                float lv = wcs[k][quad * 32 + cc];
                acc1[cc] += lv * w1;
                acc2[cc] += lv * w2;
            }
        }
    }
#pragma unroll
    for (int cc = 0; cc < 32; cc++) {
        int c = quad * 32 + cc;
        bpack[((size_t)(na >> 3) * NCP + c) * 8 + (na & 7)] = f2bf(acc1[cc]);
        bpack[((size_t)(nb >> 3) * NCP + c) * 8 + (nb & 7)] = f2bf(acc2[cc]);
    }
}

// K9a: out init with b_cls
__global__ void k_init(float* __restrict__ out, const float* __restrict__ bc) {
    int i = blockIdx.x * 256 + threadIdx.x;
    if (i < NEF * NCLS) out[i] = bc[i % NCLS];
}

// K9: MFMA logits. out[m,c] += sum over K-slice of bl[m,k]*Wf[c,k],
// bl generated on the fly in A-fragment layout from zh/zt LDS tiles.
// Grid (NEF/64, 24): M-tile 64, K-slice 2048, fp32 atomic accumulation.
#define ZTP 88
#define ZHP 48
__global__ __launch_bounds__(256, 2) void k_logits(const ushort* __restrict__ zb,
                                                   const ushort* __restrict__ bpack,
                                                   float* __restrict__ out) {
    __shared__ ushort zhs[64 * ZHP];
    __shared__ ushort zts[64 * ZTP];
    __shared__ ushort Bls[16384];   // 32 KB: one K=128 stage of B-fragments
    int m0 = blockIdx.x * 64;
    int kb = blockIdx.y;            // K-slice of 2048
    int kg = kb >> 1;               // which 4096-block (i*64+j space)
    int ihalf = (kb & 1) * 32;      // which half of the i range
    int tid = threadIdx.x;
    int lane = tid & 63, w = tid >> 6;
    int tt = lane >> 4, r16 = lane & 15;
    int wm = (w & 1) * 32, wn = (w >> 1) * 64;

    // zt tile: 64 rows x 64 cols (cols kg*64..+64 of the zt half)
    {
        int row = tid >> 2, c8 = (tid & 3) * 16;
        const ushort* src = zb + (size_t)(m0 + row) * 1536 + 768 + kg * 64 + c8;
        uint4 v0 = *(const uint4*)src;
        uint4 v1 = *(const uint4*)(src + 8);
        *(uint4*)&zts[row * ZTP + c8] = v0;
        *(uint4*)&zts[row * ZTP + c8 + 8] = v1;
    }
    // zh tile: 64 rows x 32 cols (cols kg*64+ihalf..+32 of the zh half)
    {
        int row = tid >> 2, c8 = (tid & 3) * 8;
        const ushort* src = zb + (size_t)(m0 + row) * 1536 + kg * 64 + ihalf + c8;
        *(uint4*)&zhs[row * ZHP + c8] = *(const uint4*)src;
    }

    f32x4 acc[2][4];
    f32x4 zero = {0.f, 0.f, 0.f, 0.f};
#pragma unroll
    for (int t = 0; t < 2; t++)
#pragma unroll
        for (int n = 0; n < 4; n++) acc[t][n] = zero;

    const char* bbase = (const char*)bpack + (size_t)kb * 2048 * 256;
    for (int g = 0; g < 16; g++) {
        __syncthreads();
        const char* sb = bbase + (size_t)g * 32768;
#pragma unroll
        for (int q = 0; q < 8; q++) {
            int off = (q * 4 + w) * 1024;
            __builtin_amdgcn_global_load_lds(
                (const __attribute__((address_space(1))) void*)(sb + off + lane * 16),
                (__attribute__((address_space(3))) void*)((char*)Bls + off),
                16, 0, 0);
        }
        __syncthreads();
#pragma unroll
        for (int ks = 0; ks < 4; ks++) {
            int s = g * 4 + ks;
            int il = s >> 1;            // i within this slice's half
            int j0 = (s & 1) * 32;      // j chunk base
            bf16x8 af[2];
#pragma unroll
            for (int t = 0; t < 2; t++) {
                int row = wm + t * 16 + r16;
                float zhf = __uint_as_float((uint)zhs[row * ZHP + il] << 16);
                union { bf16x8 v; uint u[4]; } zt8, a;
                zt8.v = *(const bf16x8*)&zts[row * ZTP + j0 + tt * 8];
#pragma unroll
                for (int q = 0; q < 4; q++) {
                    uint p = zt8.u[q];
                    uint lo = __float_as_uint(__uint_as_float(p << 16) * zhf);
                    uint hi = __float_as_uint(__uint_as_float(p & 0xFFFF0000u) * zhf);
                    a.u[q] = (lo >> 16) | (hi & 0xFFFF0000u);   // truncate-to-bf16 pair
                }
                af[t] = a.v;
            }
#pragma unroll
            for (int n = 0; n < 4; n++) {
                bf16x8 bf = *(const bf16x8*)&Bls[(size_t)((ks * 4 + tt) * NCP + wn + n * 16 + r16) * 8];
                acc[0][n] = __builtin_amdgcn_mfma_f32_16x16x32_bf16(af[0], bf, acc[0][n], 0, 0, 0);
                acc[1][n] = __builtin_amdgcn_mfma_f32_16x16x32_bf16(af[1], bf, acc[1][n], 0, 0, 0);
            }
        }
    }
    // epilogue: C/D layout col=lane&15, row=(lane>>4)*4+reg   [m89-verified]
    int rbase = (lane >> 4) * 4;
#pragma unroll
    for (int t = 0; t < 2; t++)
#pragma unroll
        for (int n = 0; n < 4; n++) {
            int c = wn + n * 16 + r16;
            if (c < NCLS) {
                int row = m0 + wm + t * 16 + rbase;
#pragma unroll
                for (int r = 0; r < 4; r++)
                    atomicAdd(&out[(size_t)(row + r) * NCLS + c], acc[t][n][r]);
            }
        }
}

// ---------------------------------------------------------------------------
extern "C" void kernel_launch(void* const* d_in, const int* in_sizes, int n_in,
                              void* d_out, int out_size, void* d_ws, size_t ws_size,
                              hipStream_t stream) {
    const float* seq  = (const float*)d_in[0];
    const float* attn = (const float*)d_in[1];
    const int*   ms   = (const int*)d_in[2];
    const int*   cs   = (const int*)d_in[3];
    const float* Wh   = (const float*)d_in[4];
    const float* bh   = (const float*)d_in[5];
    const float* Wt   = (const float*)d_in[6];
    const float* bt   = (const float*)d_in[7];
    const float* Wp   = (const float*)d_in[8];
    const float* Wc   = (const float*)d_in[9];
    const float* bc   = (const float*)d_in[10];
    float* out = (float*)d_out;

    // Workspace (floats). Region B is reused: gather scratch dies after k_tanh,
    // then bpack (bf16 Wf) overlays it. zb sits past both live ranges.
    float* w     = (float*)d_ws;
    float* rsW   = w;                        // 1,769,472
    float* regB  = w + 1769472;
    float* e_att = regB;                     // 589,824
    float* gate  = e_att + 589824;           // 49,152
    float* ht    = gate + 49152;             // 1,179,648
    float* rs    = ht + 1179648;             // 884,736
    float* eemb  = rs + 884736;              // 36,864
    float* hsW   = eemb + 36864;             // 36,864
    float* tsW   = hsW + 36864;              // 36,864  (regB ends at +2,813,952)
    ushort* bpack = (ushort*)regB;           // 6,291,456 bf16 (overlays e_att..tsW, written after k_tanh)
    ushort* zb    = (ushort*)(regB + 3145728); // 1,769,472 bf16

    k_eatt<<<BB * NEE * NHH, 256, 0, stream>>>(attn, ms, e_att);
    k_gate<<<BB * NEE, 256, 0, stream>>>(e_att, gate);
    k_eemb<<<BB * NEE, 256, 0, stream>>>(seq, gate, ms, cs, eemb);
    k_ht<<<NEF, 256, 0, stream>>>(e_att, ht);
    k_rs<<<dim3(BB * NEE, 3), 256, 0, stream>>>(seq, ht, rs);
    k_hw<<<dim3(48, 2, 12), 256, 0, stream>>>(eemb, Wh, Wt, hsW, tsW);
    k_rsw<<<dim3(NEF / 64, 2 * HH / 64), 256, 0, stream>>>(rs, Wh, Wt, rsW);
    k_tanh<<<(NEF * 2 * HH + 255) / 256, 256, 0, stream>>>(rsW, hsW, tsW, bh, bt, zb);
    k_wf<<<HB / 128, 256, 0, stream>>>(Wp, Wc, bpack);     // after k_tanh: clobbers hsW/tsW region
    k_init<<<(NEF * NCLS + 255) / 256, 256, 0, stream>>>(out, bc);
    k_logits<<<dim3(NEF / 64, 24), 256, 0, stream>>>(zb, bpack, out);
}

// Round 4
// 679.163 us; speedup vs baseline: 5.1862x; 1.4544x over previous
//
#include <hip/hip_runtime.h>
#include <math.h>

// Problem constants
#define BB   2
#define LL   1024
#define HH   768
#define NHH  12
#define NEE  24
#define MMM  3
#define NCC  2
#define CWW  8
#define BLK  64
#define NCLS 97
#define KB   12          // HH/BLK
#define HB   49152       // HH*BLK
#define NCP  128         // padded class dim for Wf
#define NCT  7           // class tiles computed (112 >= 97)
#define NEF  1152        // BB*NEE*NEE

typedef unsigned int uint;
typedef unsigned short ushort;
typedef __attribute__((ext_vector_type(8))) short bf16x8;
typedef __attribute__((ext_vector_type(4))) float f32x4;

// round-to-nearest-even fp32 -> bf16
__device__ __forceinline__ ushort f2bf(float f) {
    uint u = __float_as_uint(f);
    u += 0x7fffu + ((u >> 16) & 1u);
    return (ushort)(u >> 16);
}

// ---------------------------------------------------------------------------
// K1: e_att[b,e,h,l] = mean_m attention[b,h,ms[b,e,m]+1,l]
__global__ void k_eatt(const float* __restrict__ att_in, const int* __restrict__ ms,
                       float* __restrict__ e_att) {
    int blk = blockIdx.x;               // (b*NEE+e)*NHH + h
    int h = blk % NHH;
    int e = (blk / NHH) % NEE;
    int b = blk / (NHH * NEE);
    int base = (b * NEE + e) * MMM;
    int p0 = ms[base + 0] + 1;
    int p1 = ms[base + 1] + 1;
    int p2 = ms[base + 2] + 1;
    const float* r0 = att_in + ((size_t)(b * NHH + h) * LL + p0) * LL;
    const float* r1 = att_in + ((size_t)(b * NHH + h) * LL + p1) * LL;
    const float* r2 = att_in + ((size_t)(b * NHH + h) * LL + p2) * LL;
    float* o = e_att + ((size_t)(b * NEE + e) * NHH + h) * LL;
    for (int l = threadIdx.x; l < LL; l += blockDim.x)
        o[l] = (r0[l] + r1[l] + r2[l]) * (1.f / 3.f);
}

// K2: gate[b,e,l] = att[l]/sum_l att[l], att[l]=sum_h e_att
__global__ void k_gate(const float* __restrict__ e_att, float* __restrict__ gate) {
    int be = blockIdx.x;
    __shared__ float att_s[LL];
    __shared__ float red[4];
    const float* ea = e_att + (size_t)be * NHH * LL;
    float lsum = 0.f;
    for (int l = threadIdx.x; l < LL; l += blockDim.x) {
        float a = 0.f;
        for (int h = 0; h < NHH; h++) a += ea[h * LL + l];
        att_s[l] = a;
        lsum += a;
    }
    for (int off = 32; off; off >>= 1) lsum += __shfl_down(lsum, off, 64);
    if ((threadIdx.x & 63) == 0) red[threadIdx.x >> 6] = lsum;
    __syncthreads();
    float inv = 1.f / (red[0] + red[1] + red[2] + red[3]);
    for (int l = threadIdx.x; l < LL; l += blockDim.x)
        gate[(size_t)be * LL + l] = att_s[l] * inv;
}

// K3: e_emb[b,e,d] = logsumexp over {3 mention embeds, 2 coref embeds}
__global__ void k_eemb(const float* __restrict__ seq, const float* __restrict__ gate,
                       const int* __restrict__ ms, const int* __restrict__ cs,
                       float* __restrict__ e_emb) {
    int be = blockIdx.x;
    int b = be / NEE;
    int p0 = ms[be * MMM + 0] + 1, p1 = ms[be * MMM + 1] + 1, p2 = ms[be * MMM + 2] + 1;
    int c0 = cs[be * NCC + 0], c1 = cs[be * NCC + 1];
    for (int d = threadIdx.x; d < HH; d += blockDim.x) {
        float v0 = seq[((size_t)b * LL + p0) * HH + d];
        float v1 = seq[((size_t)b * LL + p1) * HH + d];
        float v2 = seq[((size_t)b * LL + p2) * HH + d];
        float s0 = 0.f, s1 = 0.f;
        for (int w = 0; w < CWW; w++) {
            s0 += gate[(size_t)be * LL + c0 + w] * seq[((size_t)b * LL + c0 + w) * HH + d];
            s1 += gate[(size_t)be * LL + c1 + w] * seq[((size_t)b * LL + c1 + w) * HH + d];
        }
        float mx = fmaxf(fmaxf(fmaxf(v0, v1), fmaxf(v2, s0)), s1);
        float s = expf(v0 - mx) + expf(v1 - mx) + expf(v2 - mx) + expf(s0 - mx) + expf(s1 - mx);
        e_emb[(size_t)be * HH + d] = logf(s) + mx;
    }
}

// K4: ht[b,e,f,l] = relu(sum_h e_att[b,e,h,l]*e_att[b,f,h,l]) normalized over l
__global__ void k_ht(const float* __restrict__ e_att, float* __restrict__ ht) {
    int blk = blockIdx.x;   // ((b*NEE+e)*NEE+f)
    int f = blk % NEE;
    int e = (blk / NEE) % NEE;
    int b = blk / (NEE * NEE);
    const float* ea = e_att + (size_t)(b * NEE + e) * NHH * LL;
    const float* fa = e_att + (size_t)(b * NEE + f) * NHH * LL;
    __shared__ float hts[LL];
    __shared__ float red[4];
    float lsum = 0.f;
    for (int l = threadIdx.x; l < LL; l += blockDim.x) {
        float s = 0.f;
        for (int h = 0; h < NHH; h++) s += ea[h * LL + l] * fa[h * LL + l];
        s = fmaxf(s, 0.f);
        hts[l] = s;
        lsum += s;
    }
    for (int off = 32; off; off >>= 1) lsum += __shfl_down(lsum, off, 64);
    if ((threadIdx.x & 63) == 0) red[threadIdx.x >> 6] = lsum;
    __syncthreads();
    float inv = 1.f / (red[0] + red[1] + red[2] + red[3] + 1e-10f);
    for (int l = threadIdx.x; l < LL; l += blockDim.x)
        ht[(size_t)blk * LL + l] = hts[l] * inv;
}

// K5: rs[b,e,f,d] = sum_l ht[b,e,f,l]*seq[b,l,d]
__global__ void k_rs(const float* __restrict__ seq, const float* __restrict__ ht,
                     float* __restrict__ rs) {
    int be = blockIdx.x;
    int b = be / NEE;
    int d = blockIdx.y * 256 + threadIdx.x;
    __shared__ float hl[NEE][256];
    float acc[NEE];
#pragma unroll
    for (int f = 0; f < NEE; f++) acc[f] = 0.f;
    for (int lc = 0; lc < LL; lc += 256) {
        __syncthreads();
        for (int idx = threadIdx.x; idx < NEE * 256; idx += 256) {
            int f = idx >> 8, l = idx & 255;
            hl[f][l] = ht[((size_t)be * NEE + f) * LL + lc + l];
        }
        __syncthreads();
        for (int l = 0; l < 256; l++) {
            float sv = seq[((size_t)b * LL + lc + l) * HH + d];
#pragma unroll
            for (int f = 0; f < NEE; f++) acc[f] += hl[f][l] * sv;
        }
    }
    for (int f = 0; f < NEE; f++)
        rs[((size_t)be * NEE + f) * HH + d] = acc[f];
}

// K6a: hsW[m2,d] = sum_j e_emb[m2,j]*Wm[d,j] (first HH cols of Wh/Wt).
__global__ void k_hw(const float* __restrict__ e_emb, const float* __restrict__ Wh,
                     const float* __restrict__ Wt, float* __restrict__ hsW,
                     float* __restrict__ tsW) {
    int m2 = blockIdx.x;          // 0..47
    int which = blockIdx.y;       // 0..1
    int chunk = blockIdx.z;       // 0..11 (64 d's each)
    const float* Wm = which ? Wt : Wh;
    float* outp = which ? tsW : hsW;
    __shared__ float xs[HH];
    const float* x = e_emb + (size_t)m2 * HH;
    for (int j = threadIdx.x; j < HH; j += 256) xs[j] = x[j];
    __syncthreads();
    int lane = threadIdx.x & 63, w = threadIdx.x >> 6;
    int d0 = chunk * 64 + w * 16;
#pragma unroll 4
    for (int i = 0; i < 16; i++) {
        int d = d0 + i;
        const float* wr = Wm + (size_t)d * (2 * HH);
        float s = 0.f;
#pragma unroll
        for (int jj = 0; jj < 12; jj++) s += xs[lane + jj * 64] * wr[lane + jj * 64];
        for (int off = 32; off; off >>= 1) s += __shfl_down(s, off, 64);
        if (lane == 0) outp[(size_t)m2 * HH + d] = s;
    }
}

// K6b: rsW[m,n] = sum_k rs[m,k] * W2[n,k], W2 = [W_head[:,768:]; W_tail[:,768:]]
__global__ void k_rsw(const float* __restrict__ rs, const float* __restrict__ Wh,
                      const float* __restrict__ Wt, float* __restrict__ rsW) {
    int m0 = blockIdx.x * 64, n0 = blockIdx.y * 64;
    __shared__ float As[16][68], Bs[16][68];
    int tx = threadIdx.x & 15, ty = threadIdx.x >> 4;
    int lr = threadIdx.x >> 2;          // 0..63
    int lk = (threadIdx.x & 3) * 4;     // 0,4,8,12
    float acc[4][4] = {};
    int n = n0 + lr;
    const float* brow = (n < HH) ? (Wh + (size_t)n * (2 * HH) + HH)
                                 : (Wt + (size_t)(n - HH) * (2 * HH) + HH);
    const float* arow = rs + (size_t)(m0 + lr) * HH;
    for (int k0 = 0; k0 < HH; k0 += 16) {
        float4 av = *(const float4*)(arow + k0 + lk);
        float4 bv = *(const float4*)(brow + k0 + lk);
        __syncthreads();
        As[lk + 0][lr] = av.x; As[lk + 1][lr] = av.y; As[lk + 2][lr] = av.z; As[lk + 3][lr] = av.w;
        Bs[lk + 0][lr] = bv.x; Bs[lk + 1][lr] = bv.y; Bs[lk + 2][lr] = bv.z; Bs[lk + 3][lr] = bv.w;
        __syncthreads();
#pragma unroll
        for (int kk = 0; kk < 16; kk++) {
            float a0 = As[kk][ty * 4 + 0], a1 = As[kk][ty * 4 + 1];
            float a2 = As[kk][ty * 4 + 2], a3 = As[kk][ty * 4 + 3];
            float b0 = Bs[kk][tx * 4 + 0], b1 = Bs[kk][tx * 4 + 1];
            float b2 = Bs[kk][tx * 4 + 2], b3 = Bs[kk][tx * 4 + 3];
            acc[0][0] += a0 * b0; acc[0][1] += a0 * b1; acc[0][2] += a0 * b2; acc[0][3] += a0 * b3;
            acc[1][0] += a1 * b0; acc[1][1] += a1 * b1; acc[1][2] += a1 * b2; acc[1][3] += a1 * b3;
            acc[2][0] += a2 * b0; acc[2][1] += a2 * b1; acc[2][2] += a2 * b2; acc[2][3] += a2 * b3;
            acc[3][0] += a3 * b0; acc[3][1] += a3 * b1; acc[3][2] += a3 * b2; acc[3][3] += a3 * b3;
        }
    }
#pragma unroll
    for (int i = 0; i < 4; i++)
#pragma unroll
        for (int j = 0; j < 4; j++)
            rsW[(size_t)(m0 + ty * 4 + i) * (2 * HH) + n0 + tx * 4 + j] = acc[i][j];
}

// K7: zb = bf16(tanh(rsW + hsW/tsW + bias)).  hs uses e_emb[b,e], ts uses e_emb[b,f]
__global__ void k_tanh(const float* __restrict__ rsW, const float* __restrict__ hsW,
                       const float* __restrict__ tsW, const float* __restrict__ bh,
                       const float* __restrict__ bt, ushort* __restrict__ zb) {
    size_t i = (size_t)blockIdx.x * 256 + threadIdx.x;
    if (i >= (size_t)NEF * 2 * HH) return;
    int nn = (int)(i % (2 * HH));
    int m = (int)(i / (2 * HH));
    int f = m % NEE;
    int e = (m / NEE) % NEE;
    int b = m / (NEE * NEE);
    float v = rsW[i];
    if (nn < HH) v = tanhf(v + hsW[(size_t)(b * NEE + e) * HH + nn] + bh[nn]);
    else {
        int d = nn - HH;
        v = tanhf(v + tsW[(size_t)(b * NEE + f) * HH + d] + bt[d]);
    }
    zb[i] = f2bf(v);
}

// K8a: pre-pack W_cls into bf16 MFMA-B-fragment order (one uint4 per thread):
// wcpack[((kc*NCT + ct)*64 + lane)*8 + j] = bf16(Wc[(ct*16 + (lane&15))*HH +
//                                                    kc*32 + (lane>>4)*8 + j]), 0 if c>=NCLS
__global__ void k_wcp(const float* __restrict__ Wc, ushort* __restrict__ wcpack) {
    int t = blockIdx.x * 256 + threadIdx.x;
    if (t >= 24 * NCT * 64) return;
    int kc = t / (NCT * 64);
    int r = t % (NCT * 64);
    int ct = r >> 6;
    int lane = r & 63;
    int c = ct * 16 + (lane & 15);
    int k0 = kc * 32 + (lane >> 4) * 8;
    uint u[4] = {0u, 0u, 0u, 0u};
    if (c < NCLS) {
        const float* src = Wc + (size_t)c * HH + k0;
        float4 f0 = *(const float4*)src;
        float4 f1 = *(const float4*)(src + 4);
        u[0] = (uint)f2bf(f0.x) | ((uint)f2bf(f0.y) << 16);
        u[1] = (uint)f2bf(f0.z) | ((uint)f2bf(f0.w) << 16);
        u[2] = (uint)f2bf(f1.x) | ((uint)f2bf(f1.y) << 16);
        u[3] = (uint)f2bf(f1.z) | ((uint)f2bf(f1.w) << 16);
    }
    *(uint4*)(wcpack + (size_t)t * 8) = make_uint4(u[0], u[1], u[2], u[3]);
}

// K8: bf16 MFMA GEMM for Wf: D[n, c] = sum_k Wp[k*HB + n] * Wc[c*HH + k].
// Barrier-free: A-fragments direct from global (8 dword loads, 4x64B segments,
// streams W_proj exactly once = 147 MB -> ~23 us HBM floor), B-fragments are
// single uint4 loads from L2-resident wcpack. Layout conventions identical to
// the verified k_logits (A: m=lane&15,k=tt*8+j; C/D: col=lane&15,row=tt*4+r).
// Grid 768 blocks x 4 waves (64 n per block, 16 n per wave), ~12 waves/CU.
__global__ void k_wf(const float* __restrict__ Wp, const ushort* __restrict__ wcpack,
                     ushort* __restrict__ bpack) {
    int tid = threadIdx.x;
    int lane = tid & 63, w = tid >> 6;
    int r16 = lane & 15, tt = lane >> 4;
    int n0 = blockIdx.x * 64 + w * 16;        // this wave's 16-n tile
    // A source: lane reads col n0+r16, rows tt*8 + j (j=0..7), per k-chunk
    const float* ap = Wp + (size_t)(tt * 8) * HB + n0 + r16;
    const uint4* wb = (const uint4*)wcpack;

    f32x4 acc[NCT];
    f32x4 zero = {0.f, 0.f, 0.f, 0.f};
#pragma unroll
    for (int ct = 0; ct < NCT; ct++) acc[ct] = zero;

    for (int kc = 0; kc < 24; kc++) {
        const float* a0 = ap + (size_t)(kc * 32) * HB;
        float f[8];
#pragma unroll
        for (int j = 0; j < 8; j++) f[j] = a0[(size_t)j * HB];
        union { bf16x8 v; uint u[4]; } a;
#pragma unroll
        for (int q = 0; q < 4; q++)
            a.u[q] = (__float_as_uint(f[2 * q]) >> 16) |
                     (__float_as_uint(f[2 * q + 1]) & 0xFFFF0000u);  // truncate pair
#pragma unroll
        for (int ct = 0; ct < NCT; ct++) {
            union { uint4 q; bf16x8 v; } b;
            b.q = wb[(size_t)(kc * NCT + ct) * 64 + lane];
            acc[ct] = __builtin_amdgcn_mfma_f32_16x16x32_bf16(a.v, b.v, acc[ct], 0, 0, 0);
        }
    }
    // store: n = n0 + tt*4 + r (C/D row), c = ct*16 + r16 (C/D col)
#pragma unroll
    for (int ct = 0; ct < NCT; ct++) {
        int c = ct * 16 + r16;
#pragma unroll
        for (int r = 0; r < 4; r++) {
            int n = n0 + tt * 4 + r;
            bpack[((size_t)(n >> 3) * NCP + c) * 8 + (n & 7)] = f2bf(acc[ct][r]);
        }
    }
}

// K9a: out init with b_cls
__global__ void k_init(float* __restrict__ out, const float* __restrict__ bc) {
    int i = blockIdx.x * 256 + threadIdx.x;
    if (i < NEF * NCLS) out[i] = bc[i % NCLS];
}

// K9: MFMA logits. out[m,c] += sum over K-slice of bl[m,k]*Wf[c,k],
// bl generated on the fly in A-fragment layout from zh/zt LDS tiles.
// Grid (NEF/64, 24): M-tile 64, K-slice 2048, fp32 atomic accumulation.
#define ZTP 88
#define ZHP 48
__global__ __launch_bounds__(256, 2) void k_logits(const ushort* __restrict__ zb,
                                                   const ushort* __restrict__ bpack,
                                                   float* __restrict__ out) {
    __shared__ ushort zhs[64 * ZHP];
    __shared__ ushort zts[64 * ZTP];
    __shared__ ushort Bls[16384];   // 32 KB: one K=128 stage of B-fragments
    int m0 = blockIdx.x * 64;
    int kb = blockIdx.y;            // K-slice of 2048
    int kg = kb >> 1;               // which 4096-block (i*64+j space)
    int ihalf = (kb & 1) * 32;      // which half of the i range
    int tid = threadIdx.x;
    int lane = tid & 63, w = tid >> 6;
    int tt = lane >> 4, r16 = lane & 15;
    int wm = (w & 1) * 32, wn = (w >> 1) * 64;

    // zt tile: 64 rows x 64 cols (cols kg*64..+64 of the zt half)
    {
        int row = tid >> 2, c8 = (tid & 3) * 16;
        const ushort* src = zb + (size_t)(m0 + row) * 1536 + 768 + kg * 64 + c8;
        uint4 v0 = *(const uint4*)src;
        uint4 v1 = *(const uint4*)(src + 8);
        *(uint4*)&zts[row * ZTP + c8] = v0;
        *(uint4*)&zts[row * ZTP + c8 + 8] = v1;
    }
    // zh tile: 64 rows x 32 cols (cols kg*64+ihalf..+32 of the zh half)
    {
        int row = tid >> 2, c8 = (tid & 3) * 8;
        const ushort* src = zb + (size_t)(m0 + row) * 1536 + kg * 64 + ihalf + c8;
        *(uint4*)&zhs[row * ZHP + c8] = *(const uint4*)src;
    }

    f32x4 acc[2][4];
    f32x4 zero = {0.f, 0.f, 0.f, 0.f};
#pragma unroll
    for (int t = 0; t < 2; t++)
#pragma unroll
        for (int n = 0; n < 4; n++) acc[t][n] = zero;

    const char* bbase = (const char*)bpack + (size_t)kb * 2048 * 256;
    for (int g = 0; g < 16; g++) {
        __syncthreads();
        const char* sb = bbase + (size_t)g * 32768;
#pragma unroll
        for (int q = 0; q < 8; q++) {
            int off = (q * 4 + w) * 1024;
            __builtin_amdgcn_global_load_lds(
                (const __attribute__((address_space(1))) void*)(sb + off + lane * 16),
                (__attribute__((address_space(3))) void*)((char*)Bls + off),
                16, 0, 0);
        }
        __syncthreads();
#pragma unroll
        for (int ks = 0; ks < 4; ks++) {
            int s = g * 4 + ks;
            int il = s >> 1;            // i within this slice's half
            int j0 = (s & 1) * 32;      // j chunk base
            bf16x8 af[2];
#pragma unroll
            for (int t = 0; t < 2; t++) {
                int row = wm + t * 16 + r16;
                float zhf = __uint_as_float((uint)zhs[row * ZHP + il] << 16);
                union { bf16x8 v; uint u[4]; } zt8, a;
                zt8.v = *(const bf16x8*)&zts[row * ZTP + j0 + tt * 8];
#pragma unroll
                for (int q = 0; q < 4; q++) {
                    uint p = zt8.u[q];
                    uint lo = __float_as_uint(__uint_as_float(p << 16) * zhf);
                    uint hi = __float_as_uint(__uint_as_float(p & 0xFFFF0000u) * zhf);
                    a.u[q] = (lo >> 16) | (hi & 0xFFFF0000u);   // truncate-to-bf16 pair
                }
                af[t] = a.v;
            }
#pragma unroll
            for (int n = 0; n < 4; n++) {
                bf16x8 bf = *(const bf16x8*)&Bls[(size_t)((ks * 4 + tt) * NCP + wn + n * 16 + r16) * 8];
                acc[0][n] = __builtin_amdgcn_mfma_f32_16x16x32_bf16(af[0], bf, acc[0][n], 0, 0, 0);
                acc[1][n] = __builtin_amdgcn_mfma_f32_16x16x32_bf16(af[1], bf, acc[1][n], 0, 0, 0);
            }
        }
    }
    // epilogue: C/D layout col=lane&15, row=(lane>>4)*4+reg   [m89-verified]
    int rbase = (lane >> 4) * 4;
#pragma unroll
    for (int t = 0; t < 2; t++)
#pragma unroll
        for (int n = 0; n < 4; n++) {
            int c = wn + n * 16 + r16;
            if (c < NCLS) {
                int row = m0 + wm + t * 16 + rbase;
#pragma unroll
                for (int r = 0; r < 4; r++)
                    atomicAdd(&out[(size_t)(row + r) * NCLS + c], acc[t][n][r]);
            }
        }
}

// ---------------------------------------------------------------------------
extern "C" void kernel_launch(void* const* d_in, const int* in_sizes, int n_in,
                              void* d_out, int out_size, void* d_ws, size_t ws_size,
                              hipStream_t stream) {
    const float* seq  = (const float*)d_in[0];
    const float* attn = (const float*)d_in[1];
    const int*   ms   = (const int*)d_in[2];
    const int*   cs   = (const int*)d_in[3];
    const float* Wh   = (const float*)d_in[4];
    const float* bh   = (const float*)d_in[5];
    const float* Wt   = (const float*)d_in[6];
    const float* bt   = (const float*)d_in[7];
    const float* Wp   = (const float*)d_in[8];
    const float* Wc   = (const float*)d_in[9];
    const float* bc   = (const float*)d_in[10];
    float* out = (float*)d_out;

    // Workspace (floats). Region B is reused: gather scratch dies after k_tanh,
    // then bpack (bf16 Wf) overlays it. zb and wcpack sit past both live ranges.
    float* w     = (float*)d_ws;
    float* rsW   = w;                        // 1,769,472
    float* regB  = w + 1769472;
    float* e_att = regB;                     // 589,824
    float* gate  = e_att + 589824;           // 49,152
    float* ht    = gate + 49152;             // 1,179,648
    float* rs    = ht + 1179648;             // 884,736
    float* eemb  = rs + 884736;              // 36,864
    float* hsW   = eemb + 36864;             // 36,864
    float* tsW   = hsW + 36864;              // 36,864  (regB scratch ends at +2,813,952)
    ushort* bpack  = (ushort*)regB;            // 6,291,456 bf16 (overlays scratch, written after k_tanh)
    ushort* zb     = (ushort*)(regB + 3145728); // 1,769,472 bf16
    ushort* wcpack = (ushort*)(regB + 4030464); // 86,016 bf16 (W_cls B-fragments)

    k_wcp<<<(24 * NCT * 64 + 255) / 256, 256, 0, stream>>>(Wc, wcpack);
    k_eatt<<<BB * NEE * NHH, 256, 0, stream>>>(attn, ms, e_att);
    k_gate<<<BB * NEE, 256, 0, stream>>>(e_att, gate);
    k_eemb<<<BB * NEE, 256, 0, stream>>>(seq, gate, ms, cs, eemb);
    k_ht<<<NEF, 256, 0, stream>>>(e_att, ht);
    k_rs<<<dim3(BB * NEE, 3), 256, 0, stream>>>(seq, ht, rs);
    k_hw<<<dim3(48, 2, 12), 256, 0, stream>>>(eemb, Wh, Wt, hsW, tsW);
    k_rsw<<<dim3(NEF / 64, 2 * HH / 64), 256, 0, stream>>>(rs, Wh, Wt, rsW);
    k_tanh<<<(NEF * 2 * HH + 255) / 256, 256, 0, stream>>>(rsW, hsW, tsW, bh, bt, zb);
    k_wf<<<HB / 64, 256, 0, stream>>>(Wp, wcpack, bpack);  // after k_tanh: clobbers scratch region
    k_init<<<(NEF * NCLS + 255) / 256, 256, 0, stream>>>(out, bc);
    k_logits<<<dim3(NEF / 64, 24), 256, 0, stream>>>(zb, bpack, out);
}